// Round 7
// baseline (383.857 us; speedup 1.0000x reference)
//
#include <hip/hip_runtime.h>
#include <hip/hip_bf16.h>

#define SEQ 2048
#define DM 2048
#define NH 16
#define NKV 4
#define HD 128

typedef float f32x4 __attribute__((ext_vector_type(4)));
typedef short s16x8 __attribute__((ext_vector_type(8)));
typedef short s16x4 __attribute__((ext_vector_type(4)));

__device__ inline __hip_bfloat16 f2b(float f) { return __float2bfloat16(f); }
__device__ inline float b2f_us(unsigned short u) { return __uint_as_float(((unsigned)u) << 16); }
__device__ inline short f2b_s(float f) {
    __hip_bfloat16 h = __float2bfloat16(f);
    return *(short*)&h;
}

// async global->LDS, 16B per lane; HW dest = wave-uniform base + lane*16.
__device__ inline void gl_lds16(const void* g, void* l) {
    __builtin_amdgcn_global_load_lds((const __attribute__((address_space(1))) void*)g,
                                     (__attribute__((address_space(3))) void*)l, 16, 0, 0);
}

// ---------------- fused prep: cast x->bf16  +  4x transpose_cast (weights) ----------
__global__ void prep_kernel(const float* __restrict__ x,
                            const float* __restrict__ wq, const float* __restrict__ wk,
                            const float* __restrict__ wv, const float* __restrict__ wo,
                            __hip_bfloat16* __restrict__ xb,
                            __hip_bfloat16* __restrict__ wqkvt,
                            __hip_bfloat16* __restrict__ wot) {
    __shared__ float tile[32][33];
    int bid = blockIdx.x;
    const int t = threadIdx.x;
    if (bid < 8192) {
        int i = (bid * 256 + t) * 4;
        float4 v = *(const float4*)(x + i);
        __hip_bfloat16 o4[4] = {f2b(v.x), f2b(v.y), f2b(v.z), f2b(v.w)};
        *(ushort4*)(xb + i) = *(ushort4*)o4;
        return;
    }
    bid -= 8192;
    const float* in;
    __hip_bfloat16* out;
    int N, bx, by;
    if (bid < 4096) {
        in = wq; out = wqkvt; N = 2048; bx = bid & 63; by = bid >> 6;
    } else if (bid < 5120) {
        bid -= 4096; in = wk; out = wqkvt + (size_t)2048 * 2048; N = 512; bx = bid & 15; by = bid >> 4;
    } else if (bid < 6144) {
        bid -= 5120; in = wv; out = wqkvt + (size_t)2560 * 2048; N = 512; bx = bid & 15; by = bid >> 4;
    } else {
        bid -= 6144; in = wo; out = wot; N = 2048; bx = bid & 63; by = bid >> 6;
    }
    const int K = 2048;
    int n0 = bx * 32, k0 = by * 32;
    int tx = t & 31, ty = t >> 5; // logical (32,8)
    for (int r = ty; r < 32; r += 8)
        tile[r][tx] = in[(size_t)(k0 + r) * N + n0 + tx];
    __syncthreads();
    for (int r = ty; r < 32; r += 8)
        out[(size_t)(n0 + r) * K + k0 + tx] = f2b(tile[tx][r]);
}

// ---------------- GEMM 256x256, BK=32, deep-pipelined (T2+T3+T4+T5) --------------
// C[M][N] = A[M][Kd] * Bt[N][Kd]^T.
// R14: replaces the m97 128x128 2-barrier structure (measured-equivalent ~550 TF at
// our shapes) with the documented 256^2 counted-vmcnt schedule (m198/m201 regime):
//  * 8 waves (512 thr), wave grid 2Mx4N, per-wave output 128x64, acc[8][4].
//  * LDS: 4-buffer ring, per buffer A 256x32 + B 256x32 bf16 = 32KB -> 128KB total,
//    1 block/CU.
//  * Staging: global_load_lds w/ pre-swizzled source; physical 16B-block
//    p = cb ^ ((row>>1)&3) -> a wave's b128 frag reads hit 8 distinct bank-quads
//    over 8 consecutive 64B rows (2-way over 16 = free).
//  * Pipeline: prologue stages tiles 0..2; per K-tile: counted vmcnt(8) (waits ONLY
//    the oldest tile's 4 loads; tiles t+1,t+2 stay in flight ACROSS the barrier),
//    raw s_barrier (no compiler vmcnt(0) drain!), sched_barrier(0) fence (rule #18),
//    stage tile t+3 into the buffer tile t-1 vacated, 12 ds_read_b128 + 32 MFMA
//    (setprio-wrapped). Never vmcnt(0) until the last 2 tiles.
// Sync proof: per-wave vmcnt(8) + barrier => tile t fully in LDS for all waves;
// stage(t+3) is after the barrier, and tile t-1's reads finished before each wave's
// previous MFMA cluster (compiler lgkmcnt) hence before the barrier.
template <int OUT_F32>
__global__ __launch_bounds__(512, 2) void gemm256(
    const __hip_bfloat16* __restrict__ A,
    const __hip_bfloat16* __restrict__ Bt,
    void* __restrict__ Cp, int M, int N, int Kd) {
    __shared__ __hip_bfloat16 As[4][8192]; // [buf][256 rows x 32 cols], swizzled blocks
    __shared__ __hip_bfloat16 Bs[4][8192];

    const int nx = gridDim.x, ny = gridDim.y;
    const int pid = blockIdx.y * nx + blockIdx.x;
    const int GM = 8;
    const int grp = pid / (GM * nx);
    const int first = grp * GM;
    const int gsz = (ny - first < GM) ? (ny - first) : GM;
    const int mt = first + (pid % gsz);
    const int ntile = (pid % (GM * nx)) / gsz;
    const int m0 = mt * 256, n0 = ntile * 256;

    const int t = threadIdx.x;
    const int wid = t >> 6, lane = t & 63;
    const int wr = wid >> 2, wc = wid & 3; // wave grid 2(M) x 4(N)
    const int lrow = lane & 15, quad = lane >> 4;

    f32x4 acc[8][4];
    f32x4 z4 = {0.f, 0.f, 0.f, 0.f};
#pragma unroll
    for (int i = 0; i < 8; ++i)
#pragma unroll
        for (int j = 0; j < 4; ++j) acc[i][j] = z4;

    // Stage one K-tile (A and B panels, 2+2 gl_lds per thread).
    auto stage = [&](int kt) {
        const int buf = kt & 3;
#pragma unroll
        for (int i = 0; i < 2; ++i) {
            int slot = i * 512 + t;            // 16B slot id, 1024 per matrix
            int row = slot >> 2, p = slot & 3; // physical block within 64B row
            int cb = p ^ ((row >> 1) & 3);     // logical k-block stored here
            gl_lds16(A + (size_t)(m0 + row) * Kd + kt * 32 + cb * 8, &As[buf][slot * 8]);
            gl_lds16(Bt + (size_t)(n0 + row) * Kd + kt * 32 + cb * 8, &Bs[buf][slot * 8]);
        }
    };

    const int nt = Kd >> 5; // K-tiles of 32
    stage(0); stage(1); stage(2);

    // lane-invariant part of the read swizzle: p = quad ^ ((row>>1)&3), and
    // row = (multiple of 16) + lrow  =>  (row>>1)&3 == (lrow>>1)&3.
    const int psw = quad ^ ((lrow >> 1) & 3);

    for (int kt = 0; kt < nt; ++kt) {
        // counted vmcnt: wait only the oldest in-flight tile (4 loads/thread/tile).
        if (kt < nt - 2)
            asm volatile("s_waitcnt vmcnt(8)" ::: "memory");
        else if (kt == nt - 2)
            asm volatile("s_waitcnt vmcnt(4)" ::: "memory");
        else
            asm volatile("s_waitcnt vmcnt(0)" ::: "memory");
        __builtin_amdgcn_s_barrier();
        __builtin_amdgcn_sched_barrier(0); // nothing crosses: reads stay below
        if (kt + 3 < nt) stage(kt + 3);    // into buffer tile kt-1 vacated

        const int buf = kt & 3;
        s16x8 a[8], b[4];
#pragma unroll
        for (int mi = 0; mi < 8; ++mi) {
            int rr = wr * 128 + mi * 16 + lrow;
            a[mi] = *(const s16x8*)&As[buf][rr * 32 + psw * 8];
        }
#pragma unroll
        for (int ni = 0; ni < 4; ++ni) {
            int rb = wc * 64 + ni * 16 + lrow;
            b[ni] = *(const s16x8*)&Bs[buf][rb * 32 + psw * 8];
        }
        __builtin_amdgcn_s_setprio(1);
#pragma unroll
        for (int mi = 0; mi < 8; ++mi)
#pragma unroll
            for (int ni = 0; ni < 4; ++ni)
                acc[mi][ni] = __builtin_amdgcn_mfma_f32_16x16x32_bf16(a[mi], b[ni],
                                                                      acc[mi][ni], 0, 0, 0);
        __builtin_amdgcn_s_setprio(0);
    }

#pragma unroll
    for (int mi = 0; mi < 8; ++mi)
#pragma unroll
        for (int ni = 0; ni < 4; ++ni)
#pragma unroll
            for (int r = 0; r < 4; ++r) {
                int m = m0 + wr * 128 + mi * 16 + quad * 4 + r;
                int n = n0 + wc * 64 + ni * 16 + lrow;
                if (OUT_F32)
                    ((float*)Cp)[(size_t)m * N + n] = acc[mi][ni][r];
                else
                    ((__hip_bfloat16*)Cp)[(size_t)m * N + n] = f2b(acc[mi][ni][r]);
            }
}

// ---------------- fused RoPE(q,k) + V-transpose ----------------
#define QSC 0.12751744f /* (1/sqrt(128)) * 1.4426950408889634 */
__global__ void rv_kernel(const __hip_bfloat16* __restrict__ qkv,
                          const float* __restrict__ fcos, const float* __restrict__ fsin,
                          __hip_bfloat16* __restrict__ q, __hip_bfloat16* __restrict__ k,
                          __hip_bfloat16* __restrict__ vt) {
    __shared__ __hip_bfloat16 tile[128][136];
    const int t = threadIdx.x;
    if (blockIdx.x < 4096) {
        int tok = blockIdx.x; // b*SEQ + s
        int b = tok >> 11, s = tok & 2047;
        const __hip_bfloat16* row = qkv + (size_t)tok * 3072;
        for (int it = t; it < 320; it += 256) { // 2560 elems / 8
            int col = it * 8;
            s16x8 v = *(const s16x8*)(row + col);
            int p0 = (col & 127) >> 1;
            f32x4 c4 = *(const f32x4*)(fcos + s * 64 + p0);
            f32x4 s4 = *(const f32x4*)(fsin + s * 64 + p0);
            float scl = (col < 2048) ? QSC : 1.0f;
            short outv[8];
            for (int p = 0; p < 4; ++p) {
                float x0 = b2f_us((unsigned short)v[2 * p]);
                float x1 = b2f_us((unsigned short)v[2 * p + 1]);
                outv[2 * p] = f2b_s((x0 * c4[p] - x1 * s4[p]) * scl);
                outv[2 * p + 1] = f2b_s((x0 * s4[p] + x1 * c4[p]) * scl);
            }
            int d = col & 127;
            if (col < 2048) {
                int h = col >> 7;
                *(s16x8*)(q + ((size_t)((b * NH + h) * SEQ + s)) * HD + d) = *(s16x8*)outv;
            } else {
                int h = (col - 2048) >> 7;
                *(s16x8*)(k + ((size_t)((b * NKV + h) * SEQ + s)) * HD + d) = *(s16x8*)outv;
            }
        }
        return;
    }
    int r = blockIdx.x - 4096;
    int s0 = (r & 15) * 128;
    int bh = r >> 4; // b*NKV + kvh
    int b = bh >> 2, kvh = bh & 3;
    for (int i = 0; i < 8; ++i) {
        int flat = (i * 256 + t) * 8;
        int row = flat >> 7, col = flat & 127;
        *(s16x8*)&tile[row][col] =
            *(const s16x8*)(qkv + (size_t)(b * SEQ + s0 + row) * 3072 + 2560 + kvh * 128 + col);
    }
    __syncthreads();
    for (int i = 0; i < 8; ++i) {
        int dd = i * 16 + (t >> 4);
        int ss = (t & 15) * 8;
        __hip_bfloat16 tmp[8];
        for (int j = 0; j < 8; ++j) tmp[j] = tile[ss + j][dd];
        *(s16x8*)(vt + ((size_t)((b * NKV + kvh) * HD + dd)) * SEQ + s0 + ss) = *(s16x8*)tmp;
    }
}

// ---------------- causal flash attention (GQA), 128 q-rows / 512 threads ----------------
// Unchanged from R13 (stable best: 77.2us).
__global__ __launch_bounds__(512, 4) void attn_kernel(
    const __hip_bfloat16* __restrict__ q, const __hip_bfloat16* __restrict__ k,
    const __hip_bfloat16* __restrict__ vt, __hip_bfloat16* __restrict__ o) {
    __shared__ __hip_bfloat16 Ks[2][64][136];  // keys x d, double-buffered
    __shared__ __hip_bfloat16 Vs[2][128][72];  // d x keys (key columns permuted by posOf)

    const int bh = blockIdx.y;
    const int bx = (bh < 16) ? (int)(gridDim.x - 1 - blockIdx.x) : (int)blockIdx.x;
    const int b = bh >> 4, h = bh & 15;
    const int kvh = h >> 2;
    const int t = threadIdx.x;
    const int w = t >> 6, lane = t & 63;
    const int lrow = lane & 15, quad = lane >> 4;
    const int q0 = bx * 128;
    const int qrow = q0 + w * 16 + lrow; // this lane's ONE q row (n-dim)

    const __hip_bfloat16* qp = q + ((size_t)((b * NH + h) * SEQ + qrow)) * HD;
    s16x8 qf[4];
    for (int ks = 0; ks < 4; ++ks) qf[ks] = *(const s16x8*)(qp + ks * 32 + quad * 8);

    float m_i = -1e30f, l_i = 0.f;
    f32x4 accO[8];
    f32x4 z4 = {0.f, 0.f, 0.f, 0.f};
    for (int d = 0; d < 8; ++d) accO[d] = z4;

    const __hip_bfloat16* kbase = k + ((size_t)(b * NKV + kvh) * SEQ) * HD;
    const __hip_bfloat16* vbase = vt + ((size_t)(b * NKV + kvh) * HD) * SEQ;

    s16x8 kr[2], vr[2];
    auto load_tile = [&](int kt) {
        for (int i = 0; i < 2; ++i) {
            int flat = (i * 512 + t) * 8;
            kr[i] = *(const s16x8*)(kbase + (size_t)(kt * 64 + (flat >> 7)) * HD + (flat & 127));
            vr[i] = *(const s16x8*)(vbase + (size_t)(flat >> 6) * SEQ + kt * 64 + (flat & 63));
        }
    };
    auto store_tile = [&](int bsel) {
        for (int i = 0; i < 2; ++i) {
            int flat = (i * 512 + t) * 8;
            *(s16x8*)&Ks[bsel][flat >> 7][flat & 127] = kr[i];
            int row = flat >> 6, k0 = flat & 63;
            int pb = ((k0 >> 5) << 5) | (((k0 >> 2) & 2) << 3) | (((k0 >> 4) & 1) << 2);
            s16x4 lo = {vr[i][0], vr[i][1], vr[i][2], vr[i][3]};
            s16x4 hi = {vr[i][4], vr[i][5], vr[i][6], vr[i][7]};
            *(s16x4*)&Vs[bsel][row][pb] = lo;
            *(s16x4*)&Vs[bsel][row][pb + 8] = hi;
        }
    };

    const int nkt = 2 * bx + 2; // keys [0, q0+128)
    load_tile(0);
    store_tile(0);

    for (int kt = 0; kt < nkt; ++kt) {
        const int cur = kt & 1;
        bool more = (kt + 1) < nkt;
        __syncthreads(); // buf[cur] ready (stored last iter / prologue)
        if (more) load_tile(kt + 1); // global->reg, hidden under compute
        bool wave_active = (kt * 64 <= q0 + w * 16 + 15);
        bool mtile = (kt >= 2 * bx); // tile may touch the diagonal

        if (wave_active) {
            float sv[4][4];
            __builtin_amdgcn_s_setprio(1);
            for (int nt = 0; nt < 4; ++nt) {
                f32x4 sacc = z4;
                for (int ks = 0; ks < 4; ++ks) {
                    s16x8 kf = *(const s16x8*)&Ks[cur][nt * 16 + lrow][ks * 32 + quad * 8];
                    sacc = __builtin_amdgcn_mfma_f32_16x16x32_bf16(kf, qf[ks], sacc, 0, 0, 0);
                }
                if (mtile) {
                    for (int r = 0; r < 4; ++r) {
                        int key = kt * 64 + nt * 16 + quad * 4 + r;
                        sv[nt][r] = (key > qrow) ? -1e30f : sacc[r];
                    }
                } else {
                    for (int r = 0; r < 4; ++r) sv[nt][r] = sacc[r];
                }
            }
            __builtin_amdgcn_s_setprio(0);
            float mt2 = fmaxf(fmaxf(fmaxf(sv[0][0], sv[0][1]), fmaxf(sv[0][2], sv[0][3])),
                              fmaxf(fmaxf(sv[1][0], sv[1][1]), fmaxf(sv[1][2], sv[1][3])));
            mt2 = fmaxf(mt2,
                        fmaxf(fmaxf(fmaxf(sv[2][0], sv[2][1]), fmaxf(sv[2][2], sv[2][3])),
                              fmaxf(fmaxf(sv[3][0], sv[3][1]), fmaxf(sv[3][2], sv[3][3]))));
            mt2 = fmaxf(mt2, __shfl_xor(mt2, 16, 64));
            mt2 = fmaxf(mt2, __shfl_xor(mt2, 32, 64));
            if (!__all(mt2 <= m_i + 8.f)) {
                float mn = fmaxf(m_i, mt2);
                float alpha = exp2f(m_i - mn);
                l_i *= alpha;
                for (int d = 0; d < 8; ++d)
                    for (int r = 0; r < 4; ++r) accO[d][r] *= alpha;
                m_i = mn;
            }
            float rs = 0.f;
            s16x8 pf0, pf1;
#pragma unroll
            for (int j = 0; j < 8; ++j) {
                float p0 = exp2f(sv[j >> 2][j & 3] - m_i);
                float p1 = exp2f(sv[2 + (j >> 2)][j & 3] - m_i);
                rs += p0 + p1;
                pf0[j] = f2b_s(p0);
                pf1[j] = f2b_s(p1);
            }
            rs += __shfl_xor(rs, 16, 64);
            rs += __shfl_xor(rs, 32, 64);
            l_i += rs;
            __builtin_amdgcn_s_setprio(1);
            for (int dt = 0; dt < 8; ++dt) {
                s16x8 vf0 = *(const s16x8*)&Vs[cur][dt * 16 + lrow][quad * 8];
                s16x8 vf1 = *(const s16x8*)&Vs[cur][dt * 16 + lrow][32 + quad * 8];
                accO[dt] = __builtin_amdgcn_mfma_f32_16x16x32_bf16(vf0, pf0, accO[dt], 0, 0, 0);
                accO[dt] = __builtin_amdgcn_mfma_f32_16x16x32_bf16(vf1, pf1, accO[dt], 0, 0, 0);
            }
            __builtin_amdgcn_s_setprio(0);
        }

        if (more) store_tile(1 - cur); // write buffer nobody reads this iter
    }
    float inv = 1.0f / l_i;
    __hip_bfloat16* op = o + (size_t)(b * SEQ + qrow) * DM + h * HD;
    for (int dt = 0; dt < 8; ++dt) {
        short ov[4];
        for (int r = 0; r < 4; ++r) ov[r] = f2b_s(accO[dt][r] * inv);
        *(s16x4*)(op + dt * 16 + quad * 4) = *(s16x4*)ov;
    }
}

extern "C" void kernel_launch(void* const* d_in, const int* in_sizes, int n_in,
                              void* d_out, int out_size, void* d_ws, size_t ws_size,
                              hipStream_t stream) {
    (void)in_sizes; (void)n_in; (void)out_size; (void)ws_size;
    const float* x  = (const float*)d_in[0];
    const float* fc = (const float*)d_in[1];
    const float* fs = (const float*)d_in[2];
    // d_in[3] = mask: exactly causal, applied analytically
    const float* wq = (const float*)d_in[4];
    const float* wk = (const float*)d_in[5];
    const float* wv = (const float*)d_in[6];
    const float* wo = (const float*)d_in[7];

    __hip_bfloat16* xb    = (__hip_bfloat16*)d_ws;            // [4096][2048]
    __hip_bfloat16* wqkvt = xb + (size_t)8388608;             // [3072][2048]
    __hip_bfloat16* wot   = wqkvt + (size_t)6291456;          // [2048][2048]
    __hip_bfloat16* qkv   = wot + (size_t)4194304;            // [4096][3072]
    __hip_bfloat16* qb    = xb;                               // aliases xb
    __hip_bfloat16* kb    = wqkvt;                            // aliases wqkvt
    __hip_bfloat16* vtb   = wqkvt + (size_t)2097152;
    __hip_bfloat16* attno = qkv;                              // aliases qkv

    prep_kernel<<<18432, 256, 0, stream>>>(x, wq, wk, wv, wo, xb, wqkvt, wot);
    gemm256<0><<<dim3(12, 16), 512, 0, stream>>>(xb, wqkvt, qkv, 4096, 3072, 2048);
    rv_kernel<<<4224, 256, 0, stream>>>(qkv, fc, fs, qb, kb, vtb);
    attn_kernel<<<dim3(16, 32), 512, 0, stream>>>(qb, kb, vtb, attno);
    gemm256<1><<<dim3(8, 16), 512, 0, stream>>>(attno, wot, d_out, 4096, 2048, 2048);
}

// Round 8
// 331.126 us; speedup vs baseline: 1.1592x; 1.1592x over previous
//
#include <hip/hip_runtime.h>
#include <hip/hip_bf16.h>

#define SEQ 2048
#define DM 2048
#define NH 16
#define NKV 4
#define HD 128

typedef float f32x4 __attribute__((ext_vector_type(4)));
typedef short s16x8 __attribute__((ext_vector_type(8)));
typedef short s16x4 __attribute__((ext_vector_type(4)));

__device__ inline __hip_bfloat16 f2b(float f) { return __float2bfloat16(f); }
__device__ inline float b2f_us(unsigned short u) { return __uint_as_float(((unsigned)u) << 16); }
__device__ inline short f2b_s(float f) {
    __hip_bfloat16 h = __float2bfloat16(f);
    return *(short*)&h;
}

// async global->LDS, 16B per lane; HW dest = wave-uniform base + lane*16.
__device__ inline void gl_lds16(const void* g, void* l) {
    __builtin_amdgcn_global_load_lds((const __attribute__((address_space(1))) void*)g,
                                     (__attribute__((address_space(3))) void*)l, 16, 0, 0);
}

// ---------------- fused prep: cast x->bf16  +  4x transpose_cast (weights) ----------
__global__ void prep_kernel(const float* __restrict__ x,
                            const float* __restrict__ wq, const float* __restrict__ wk,
                            const float* __restrict__ wv, const float* __restrict__ wo,
                            __hip_bfloat16* __restrict__ xb,
                            __hip_bfloat16* __restrict__ wqkvt,
                            __hip_bfloat16* __restrict__ wot) {
    __shared__ float tile[32][33];
    int bid = blockIdx.x;
    const int t = threadIdx.x;
    if (bid < 8192) {
        int i = (bid * 256 + t) * 4;
        float4 v = *(const float4*)(x + i);
        __hip_bfloat16 o4[4] = {f2b(v.x), f2b(v.y), f2b(v.z), f2b(v.w)};
        *(ushort4*)(xb + i) = *(ushort4*)o4;
        return;
    }
    bid -= 8192;
    const float* in;
    __hip_bfloat16* out;
    int N, bx, by;
    if (bid < 4096) {
        in = wq; out = wqkvt; N = 2048; bx = bid & 63; by = bid >> 6;
    } else if (bid < 5120) {
        bid -= 4096; in = wk; out = wqkvt + (size_t)2048 * 2048; N = 512; bx = bid & 15; by = bid >> 4;
    } else if (bid < 6144) {
        bid -= 5120; in = wv; out = wqkvt + (size_t)2560 * 2048; N = 512; bx = bid & 15; by = bid >> 4;
    } else {
        bid -= 6144; in = wo; out = wot; N = 2048; bx = bid & 63; by = bid >> 6;
    }
    const int K = 2048;
    int n0 = bx * 32, k0 = by * 32;
    int tx = t & 31, ty = t >> 5; // logical (32,8)
    for (int r = ty; r < 32; r += 8)
        tile[r][tx] = in[(size_t)(k0 + r) * N + n0 + tx];
    __syncthreads();
    for (int r = ty; r < 32; r += 8)
        out[(size_t)(n0 + r) * K + k0 + tx] = f2b(tile[tx][r]);
}

// ---------------- GEMM: C[M][N] = A[M][Kd] * Bt[N][Kd]^T ----------------
// m97 structure + GROUP_M=8 grouped supertile swizzle. R15: REVERTED from the 256^2
// counted-vmcnt experiment (R14: 85.8+85.1us vs this kernel's ~68+45us -- the 128^2
// tile fits our shapes exactly: 768 blocks = 3.0/CU and 512 = 2.0/CU, while 256^2
// left 25-50% of CUs idle and the coarse 1-phase pipeline hit only 24% MfmaUtil).
template <int OUT_F32>
__global__ __launch_bounds__(256, 3) void gemm_bt(
    const __hip_bfloat16* __restrict__ A,
    const __hip_bfloat16* __restrict__ Bt,
    void* __restrict__ Cp, int M, int N, int Kd) {
    __shared__ __hip_bfloat16 As[128 * 64]; // [row][64], swizzled 16B slots
    __shared__ __hip_bfloat16 Bs[128 * 64];
    const int nx = gridDim.x, ny = gridDim.y;
    const int pid = blockIdx.y * nx + blockIdx.x;
    const int GM = 8;
    const int grp = pid / (GM * nx);
    const int first = grp * GM;
    const int gsz = (ny - first < GM) ? (ny - first) : GM;
    const int mt = first + (pid % gsz);
    const int ntile = (pid % (GM * nx)) / gsz;
    const int m0 = mt * 128, n0 = ntile * 128;

    const int t = threadIdx.x;
    const int wv = t >> 6, lane = t & 63;
    const int wm = (wv >> 1) * 64, wn = (wv & 1) * 64;
    const int lrow = lane & 15, quad = lane >> 4;
    f32x4 acc[4][4];
    f32x4 z4 = {0.f, 0.f, 0.f, 0.f};
    for (int i = 0; i < 4; ++i)
        for (int j = 0; j < 4; ++j) acc[i][j] = z4;

    for (int k0 = 0; k0 < Kd; k0 += 64) {
        __syncthreads();
        for (int i = 0; i < 4; ++i) {
            int flat = i * 256 + t;          // 16B slot id
            int row = flat >> 3;
            int cb = (flat & 7) ^ (row & 7); // logical 16B-block for this slot
            gl_lds16(A + (size_t)(m0 + row) * Kd + k0 + cb * 8, &As[flat * 8]);
            gl_lds16(Bt + (size_t)(n0 + row) * Kd + k0 + cb * 8, &Bs[flat * 8]);
        }
        __syncthreads();
        for (int kk = 0; kk < 2; ++kk) {
            s16x8 af[4], bf[4];
            for (int i = 0; i < 4; ++i) {
                int ra = wm + i * 16 + lrow;
                int rb = wn + i * 16 + lrow;
                int pba = ((kk * 4 + quad) ^ (ra & 7)) * 8;
                int pbb = ((kk * 4 + quad) ^ (rb & 7)) * 8;
                af[i] = *(const s16x8*)&As[ra * 64 + pba];
                bf[i] = *(const s16x8*)&Bs[rb * 64 + pbb];
            }
            for (int i = 0; i < 4; ++i)
                for (int j = 0; j < 4; ++j)
                    acc[i][j] = __builtin_amdgcn_mfma_f32_16x16x32_bf16(af[i], bf[j],
                                                                        acc[i][j], 0, 0, 0);
        }
    }
    for (int i = 0; i < 4; ++i)
        for (int j = 0; j < 4; ++j)
            for (int r = 0; r < 4; ++r) {
                int m = m0 + wm + i * 16 + quad * 4 + r;
                int n = n0 + wn + j * 16 + lrow;
                if (OUT_F32)
                    ((float*)Cp)[(size_t)m * N + n] = acc[i][j][r];
                else
                    ((__hip_bfloat16*)Cp)[(size_t)m * N + n] = f2b(acc[i][j][r]);
            }
}

// ---------------- fused RoPE(q,k) + V-transpose ----------------
#define QSC 0.12751744f /* (1/sqrt(128)) * 1.4426950408889634 */
__global__ void rv_kernel(const __hip_bfloat16* __restrict__ qkv,
                          const float* __restrict__ fcos, const float* __restrict__ fsin,
                          __hip_bfloat16* __restrict__ q, __hip_bfloat16* __restrict__ k,
                          __hip_bfloat16* __restrict__ vt) {
    __shared__ __hip_bfloat16 tile[128][136];
    const int t = threadIdx.x;
    if (blockIdx.x < 4096) {
        int tok = blockIdx.x; // b*SEQ + s
        int b = tok >> 11, s = tok & 2047;
        const __hip_bfloat16* row = qkv + (size_t)tok * 3072;
        for (int it = t; it < 320; it += 256) { // 2560 elems / 8
            int col = it * 8;
            s16x8 v = *(const s16x8*)(row + col);
            int p0 = (col & 127) >> 1;
            f32x4 c4 = *(const f32x4*)(fcos + s * 64 + p0);
            f32x4 s4 = *(const f32x4*)(fsin + s * 64 + p0);
            float scl = (col < 2048) ? QSC : 1.0f;
            short outv[8];
            for (int p = 0; p < 4; ++p) {
                float x0 = b2f_us((unsigned short)v[2 * p]);
                float x1 = b2f_us((unsigned short)v[2 * p + 1]);
                outv[2 * p] = f2b_s((x0 * c4[p] - x1 * s4[p]) * scl);
                outv[2 * p + 1] = f2b_s((x0 * s4[p] + x1 * c4[p]) * scl);
            }
            int d = col & 127;
            if (col < 2048) {
                int h = col >> 7;
                *(s16x8*)(q + ((size_t)((b * NH + h) * SEQ + s)) * HD + d) = *(s16x8*)outv;
            } else {
                int h = (col - 2048) >> 7;
                *(s16x8*)(k + ((size_t)((b * NKV + h) * SEQ + s)) * HD + d) = *(s16x8*)outv;
            }
        }
        return;
    }
    int r = blockIdx.x - 4096;
    int s0 = (r & 15) * 128;
    int bh = r >> 4; // b*NKV + kvh
    int b = bh >> 2, kvh = bh & 3;
    for (int i = 0; i < 8; ++i) {
        int flat = (i * 256 + t) * 8;
        int row = flat >> 7, col = flat & 127;
        *(s16x8*)&tile[row][col] =
            *(const s16x8*)(qkv + (size_t)(b * SEQ + s0 + row) * 3072 + 2560 + kvh * 128 + col);
    }
    __syncthreads();
    for (int i = 0; i < 8; ++i) {
        int dd = i * 16 + (t >> 4);
        int ss = (t & 15) * 8;
        __hip_bfloat16 tmp[8];
        for (int j = 0; j < 8; ++j) tmp[j] = tile[ss + j][dd];
        *(s16x8*)(vt + ((size_t)((b * NKV + kvh) * HD + dd)) * SEQ + s0 + ss) = *(s16x8*)tmp;
    }
}

// ---------------- causal flash attention (GQA), 128 q-rows / 512 threads ----------------
// R15 occupancy experiment: counters show attn latency-bound (MfmaUtil 18, VALU 36,
// HBM 8%, Occupancy 26% with a 2-blocks/CU LDS cap). Since dbuf+1-barrier measured
// NEUTRAL vs single-buffer+2-barrier (R7->R8: 81.2->80.5), revert to SINGLE-buffered
// K and V with 2 barriers/tile: LDS 71,680 -> 35,840 B -> 4 blocks/CU (VGPR 60 <= 64
// keeps 8 waves/SIMD reachable, m69). Everything else identical to the proven R13
// attn: no Ps round-trip (V posOf permute, P feeds PV from regs), exp2-domain softmax
// on pre-scaled Q, defer-max, setprio, anti-correlated q-tile mapping.
__global__ __launch_bounds__(512, 4) void attn_kernel(
    const __hip_bfloat16* __restrict__ q, const __hip_bfloat16* __restrict__ k,
    const __hip_bfloat16* __restrict__ vt, __hip_bfloat16* __restrict__ o) {
    __shared__ __hip_bfloat16 Ks[64][136];  // keys x d, single buffer
    __shared__ __hip_bfloat16 Vs[128][72];  // d x keys (key columns permuted by posOf)

    const int bh = blockIdx.y;
    const int bx = (bh < 16) ? (int)(gridDim.x - 1 - blockIdx.x) : (int)blockIdx.x;
    const int b = bh >> 4, h = bh & 15;
    const int kvh = h >> 2;
    const int t = threadIdx.x;
    const int w = t >> 6, lane = t & 63;
    const int lrow = lane & 15, quad = lane >> 4;
    const int q0 = bx * 128;
    const int qrow = q0 + w * 16 + lrow; // this lane's ONE q row (n-dim)

    // Q fragments, B-operand role: n=qrow (lrow), k=d (quad*8+j). Pre-scaled in rope.
    const __hip_bfloat16* qp = q + ((size_t)((b * NH + h) * SEQ + qrow)) * HD;
    s16x8 qf[4];
    for (int ks = 0; ks < 4; ++ks) qf[ks] = *(const s16x8*)(qp + ks * 32 + quad * 8);

    float m_i = -1e30f, l_i = 0.f;
    f32x4 accO[8];
    f32x4 z4 = {0.f, 0.f, 0.f, 0.f};
    for (int d = 0; d < 8; ++d) accO[d] = z4;

    const __hip_bfloat16* kbase = k + ((size_t)(b * NKV + kvh) * SEQ) * HD;
    const __hip_bfloat16* vbase = vt + ((size_t)(b * NKV + kvh) * HD) * SEQ;

    s16x8 kr[2], vr[2];
    auto load_tile = [&](int kt) {
        for (int i = 0; i < 2; ++i) {
            int flat = (i * 512 + t) * 8;
            kr[i] = *(const s16x8*)(kbase + (size_t)(kt * 64 + (flat >> 7)) * HD + (flat & 127));
            vr[i] = *(const s16x8*)(vbase + (size_t)(flat >> 6) * SEQ + kt * 64 + (flat & 63));
        }
    };
    auto store_tile = [&]() {
        for (int i = 0; i < 2; ++i) {
            int flat = (i * 512 + t) * 8;
            *(s16x8*)&Ks[flat >> 7][flat & 127] = kr[i];
            // V: permuted key columns. Lane holds keys k0..k0+7 (k0 = 8-aligned);
            // they land at posOf base..base+3 and base+8..base+11.
            int row = flat >> 6, k0 = flat & 63;
            int pb = ((k0 >> 5) << 5) | (((k0 >> 2) & 2) << 3) | (((k0 >> 4) & 1) << 2);
            s16x4 lo = {vr[i][0], vr[i][1], vr[i][2], vr[i][3]};
            s16x4 hi = {vr[i][4], vr[i][5], vr[i][6], vr[i][7]};
            *(s16x4*)&Vs[row][pb] = lo;
            *(s16x4*)&Vs[row][pb + 8] = hi;
        }
    };

    const int nkt = 2 * bx + 2; // keys [0, q0+128)
    load_tile(0);
    store_tile();

    for (int kt = 0; kt < nkt; ++kt) {
        bool more = (kt + 1) < nkt;
        __syncthreads(); // K/V tile stored and visible
        if (more) load_tile(kt + 1); // global->reg, hidden under compute
        bool wave_active = (kt * 64 <= q0 + w * 16 + 15);
        bool mtile = (kt >= 2 * bx); // tile may touch the diagonal

        if (wave_active) {
            float sv[4][4];
            __builtin_amdgcn_s_setprio(1);
            for (int nt = 0; nt < 4; ++nt) {
                f32x4 sacc = z4;
                for (int ks = 0; ks < 4; ++ks) {
                    s16x8 kf = *(const s16x8*)&Ks[nt * 16 + lrow][ks * 32 + quad * 8];
                    sacc = __builtin_amdgcn_mfma_f32_16x16x32_bf16(kf, qf[ks], sacc, 0, 0, 0);
                }
                if (mtile) {
                    for (int r = 0; r < 4; ++r) {
                        int key = kt * 64 + nt * 16 + quad * 4 + r;
                        sv[nt][r] = (key > qrow) ? -1e30f : sacc[r];
                    }
                } else {
                    for (int r = 0; r < 4; ++r) sv[nt][r] = sacc[r];
                }
            }
            __builtin_amdgcn_s_setprio(0);
            float mt2 = fmaxf(fmaxf(fmaxf(sv[0][0], sv[0][1]), fmaxf(sv[0][2], sv[0][3])),
                              fmaxf(fmaxf(sv[1][0], sv[1][1]), fmaxf(sv[1][2], sv[1][3])));
            mt2 = fmaxf(mt2,
                        fmaxf(fmaxf(fmaxf(sv[2][0], sv[2][1]), fmaxf(sv[2][2], sv[2][3])),
                              fmaxf(fmaxf(sv[3][0], sv[3][1]), fmaxf(sv[3][2], sv[3][3]))));
            mt2 = fmaxf(mt2, __shfl_xor(mt2, 16, 64));
            mt2 = fmaxf(mt2, __shfl_xor(mt2, 32, 64));
            // defer-max: only rescale when the running max grew by >8 (exp2 domain,
            // deferred p bounded by 2^8 -- safe in f32/bf16).
            if (!__all(mt2 <= m_i + 8.f)) {
                float mn = fmaxf(m_i, mt2);
                float alpha = exp2f(m_i - mn);
                l_i *= alpha;
                for (int d = 0; d < 8; ++d)
                    for (int r = 0; r < 4; ++r) accO[d][r] *= alpha;
                m_i = mn;
            }
            // P built fully in-register; k-slot (quad,j) of PV mfma#0 is permuted
            // position quad*8+j  <->  key (j>>2)*16 + quad*4 + (j&3) = sv[j>>2][j&3].
            float rs = 0.f;
            s16x8 pf0, pf1;
#pragma unroll
            for (int j = 0; j < 8; ++j) {
                float p0 = exp2f(sv[j >> 2][j & 3] - m_i);
                float p1 = exp2f(sv[2 + (j >> 2)][j & 3] - m_i);
                rs += p0 + p1;
                pf0[j] = f2b_s(p0);
                pf1[j] = f2b_s(p1);
            }
            rs += __shfl_xor(rs, 16, 64);
            rs += __shfl_xor(rs, 32, 64);
            l_i += rs;
            __builtin_amdgcn_s_setprio(1);
            for (int dt = 0; dt < 8; ++dt) {
                s16x8 vf0 = *(const s16x8*)&Vs[dt * 16 + lrow][quad * 8];
                s16x8 vf1 = *(const s16x8*)&Vs[dt * 16 + lrow][32 + quad * 8];
                accO[dt] = __builtin_amdgcn_mfma_f32_16x16x32_bf16(vf0, pf0, accO[dt], 0, 0, 0);
                accO[dt] = __builtin_amdgcn_mfma_f32_16x16x32_bf16(vf1, pf1, accO[dt], 0, 0, 0);
            }
            __builtin_amdgcn_s_setprio(0);
        }

        __syncthreads(); // all waves done reading Ks/Vs
        if (more) store_tile();
    }
    float inv = 1.0f / l_i;
    __hip_bfloat16* op = o + (size_t)(b * SEQ + qrow) * DM + h * HD;
    for (int dt = 0; dt < 8; ++dt) {
        short ov[4];
        for (int r = 0; r < 4; ++r) ov[r] = f2b_s(accO[dt][r] * inv);
        *(s16x4*)(op + dt * 16 + quad * 4) = *(s16x4*)ov;
    }
}

extern "C" void kernel_launch(void* const* d_in, const int* in_sizes, int n_in,
                              void* d_out, int out_size, void* d_ws, size_t ws_size,
                              hipStream_t stream) {
    (void)in_sizes; (void)n_in; (void)out_size; (void)ws_size;
    const float* x  = (const float*)d_in[0];
    const float* fc = (const float*)d_in[1];
    const float* fs = (const float*)d_in[2];
    // d_in[3] = mask: exactly causal, applied analytically
    const float* wq = (const float*)d_in[4];
    const float* wk = (const float*)d_in[5];
    const float* wv = (const float*)d_in[6];
    const float* wo = (const float*)d_in[7];

    __hip_bfloat16* xb    = (__hip_bfloat16*)d_ws;            // [4096][2048]
    __hip_bfloat16* wqkvt = xb + (size_t)8388608;             // [3072][2048]
    __hip_bfloat16* wot   = wqkvt + (size_t)6291456;          // [2048][2048]
    __hip_bfloat16* qkv   = wot + (size_t)4194304;            // [4096][3072]
    __hip_bfloat16* qb    = xb;                               // aliases xb
    __hip_bfloat16* kb    = wqkvt;                            // aliases wqkvt
    __hip_bfloat16* vtb   = wqkvt + (size_t)2097152;
    __hip_bfloat16* attno = qkv;                              // aliases qkv

    prep_kernel<<<18432, 256, 0, stream>>>(x, wq, wk, wv, wo, xb, wqkvt, wot);
    gemm_bt<0><<<dim3(24, 32), 256, 0, stream>>>(xb, wqkvt, qkv, 4096, 3072, 2048);
    rv_kernel<<<4224, 256, 0, stream>>>(qkv, fc, fs, qb, kb, vtb);
    attn_kernel<<<dim3(16, 32), 512, 0, stream>>>(qb, kb, vtb, attno);
    gemm_bt<1><<<dim3(16, 32), 256, 0, stream>>>(attno, wot, d_out, 4096, 2048, 2048);
}